// Round 3
// baseline (60.161 us; speedup 1.0000x reference)
//
#include <hip/hip_runtime.h>

// out[i] = cos^4( dot(x[i,:], W[0,:]) + b[0] )
//
// Heisenberg-picture collapse of the 12-qubit depth-4 circuit: wire 0 is only
// ever a CNOT control, so Z0 pulls back to cos^DEPTH(theta0)*Z0 plus Pauli
// strings carrying X/Y factors on wires>=1, all of which vanish in <0..0|.
// Hence the whole simulation is one mat-vec against W row 0 + cos^4.

#define K 512              // feature dim
#define WAVES_PER_BLOCK 8  // 512-thread blocks, one wave per row

// native clang vector type — __builtin_nontemporal_load requires this
// (HIP's float4 is a class and is rejected)
typedef float vf4 __attribute__((ext_vector_type(4)));

__global__ __launch_bounds__(512) void qg_expval_kernel(
    const float* __restrict__ x,   // [B, 512]
    const float* __restrict__ W,   // [12, 512] — only row 0 used
    const float* __restrict__ b,   // [12]      — only b[0] used
    float* __restrict__ out,       // [B]
    int B)
{
    const int wave = threadIdx.x >> 6;
    const int lane = threadIdx.x & 63;
    const int row  = blockIdx.x * WAVES_PER_BLOCK + wave;
    if (row >= B) return;

    const vf4* xr = (const vf4*)(x + (size_t)row * K);
    const vf4* w4 = (const vf4*)W;

    // 512 floats per row = 64 lanes * 2 * float4, fully coalesced 16B/lane.
    // x is touched exactly once -> nontemporal (bypass L2 pollution);
    // W row 0 (2 KB) is reused by every wave -> normal cached load.
    vf4 a0 = __builtin_nontemporal_load(&xr[lane]);
    vf4 a1 = __builtin_nontemporal_load(&xr[64 + lane]);
    vf4 w0 = w4[lane];
    vf4 w1 = w4[64 + lane];

    float p = a0.x * w0.x + a0.y * w0.y + a0.z * w0.z + a0.w * w0.w
            + a1.x * w1.x + a1.y * w1.y + a1.z * w1.z + a1.w * w1.w;

    // wave-64 butterfly reduction
    #pragma unroll
    for (int off = 32; off > 0; off >>= 1)
        p += __shfl_xor(p, off, 64);

    if (lane == 0) {
        float th = p + b[0];
        float c  = cosf(th);
        float c2 = c * c;
        out[row] = c2 * c2;
    }
}

extern "C" void kernel_launch(void* const* d_in, const int* in_sizes, int n_in,
                              void* d_out, int out_size, void* d_ws, size_t ws_size,
                              hipStream_t stream) {
    const float* x = (const float*)d_in[0];   // [B, 512]
    const float* W = (const float*)d_in[1];   // [12, 512]
    const float* b = (const float*)d_in[2];   // [12]
    float* out = (float*)d_out;               // [B]

    const int B = in_sizes[0] / K;            // 4096
    const int grid = (B + WAVES_PER_BLOCK - 1) / WAVES_PER_BLOCK;

    qg_expval_kernel<<<grid, 512, 0, stream>>>(x, W, b, out, B);
}